// Round 5
// baseline (93.822 us; speedup 1.0000x reference)
//
#include <hip/hip_runtime.h>
#include <stdint.h>

// Grouped linear: y[z] = coeff * x[z] @ W[idx[z]], idx sorted.
// C=8, U=V=512, Z=32768, fp32 in/out, bf16 MFMA compute.
//
// R5: W-stationary barrier-free GEMM. Per block: stage W[g][:,64-col panel]
// (64 KB, full K) into LDS once via global_load_lds from pre-tiled bf16 ws;
// one barrier; then 4 waves independently stream 64 rows of x each through
// regs (fp32->bf16) into MFMA with K-prefetch. No __syncthreads in the main
// loop -> no vmcnt(0) drains; all waits are compiler-counted.

#define Cg 8
#define Ud 512
#define Vd 512
#define Zd 32768

#define BROW 256                 // rows per block (4 waves x 64)
#define BCOL 64                  // cols per block
#define NBN 8                    // 512 / 64
#define KT 16                    // k-tiles of 32
#define BS_US 32768              // 4 ct * 16 kk * 512 us = 64 KiB
#define PER_GBN_US (4 * KT * 512)

#define NBM_MAX 135              // sum ceil(cnt_g/256) <= 128+7
#define GRID_GEMM (NBM_MAX * NBN)   // 1080

#define WSW_US (Cg * NBN * PER_GBN_US)   // 2,097,152 us = 4 MiB
#define WS_NEEDED ((size_t)WSW_US * 2 + 64)

typedef __attribute__((ext_vector_type(8))) short bf16x8;
typedef __attribute__((ext_vector_type(4))) float f32x4;
typedef __attribute__((ext_vector_type(4))) unsigned short us4;
typedef __attribute__((ext_vector_type(4))) float float4v;
typedef __attribute__((ext_vector_type(4))) unsigned int u32x4;

typedef __attribute__((address_space(3))) unsigned int lds_uint;
typedef const __attribute__((address_space(1))) unsigned int gbl_uint;

__device__ __forceinline__ unsigned short f2bf(float f) {
    unsigned int u = __float_as_uint(f);
    u += 0x7fffu + ((u >> 16) & 1u);   // round-to-nearest-even
    return (unsigned short)(u >> 16);
}
__device__ __forceinline__ unsigned int pk2(float lo, float hi) {
    return (unsigned int)f2bf(lo) | ((unsigned int)f2bf(hi) << 16);
}

// ---------------- w converter (+ group starts) ----------------
// ws layout: [g][bn(8)][ct(4)][kk(16)][subtile 512us], subtile (c,k in 16x32):
//   (k>>3)*128 + c*8 + (k&7)
// Frag read (lane l): us = ct*8192 + kk*512 + l4*128 + l15*8 -> 16 lanes
// cover 256B contiguous: conflict-free ds_read_b128.

__global__ __launch_bounds__(256)
void convert_w(const float* __restrict__ w, const int* __restrict__ idx,
               unsigned short* __restrict__ wsw, int* __restrict__ starts)
{
    const int t   = blockIdx.x * 256 + threadIdx.x;   // 524288 tasks
    const int g   = t >> 16;
    const int rem = t & 65535;
    const int u0  = (rem >> 9) << 2;                  // 4 k-rows
    const int v   = rem & 511;
    const float* src = w + ((size_t)g << 18) + (size_t)u0 * Vd + v;
    us4 p;
    p[0] = f2bf(src[0]);
    p[1] = f2bf(src[Vd]);
    p[2] = f2bf(src[2 * Vd]);
    p[3] = f2bf(src[3 * Vd]);
    const int bn = v >> 6, ct = (v >> 4) & 3, c = v & 15;
    const int kk = u0 >> 5, ks = u0 & 31;
    const int off = ((((g * NBN + bn) * 4 + ct) * KT + kk) << 9)
                  + ((ks >> 3) << 7) + (c << 3) + (ks & 7);
    *(us4*)(wsw + off) = p;

    if (blockIdx.x == 0 && threadIdx.x < 9) {
        const int gq = threadIdx.x;
        int lo = 0;
        if (gq >= 8) lo = Zd;
        else {
            int hi = Zd;
            while (lo < hi) { int mid = (lo + hi) >> 1;
                              if (idx[mid] < gq) lo = mid + 1; else hi = mid; }
        }
        starts[gq] = lo;
    }
}

// ---------------- GEMM ----------------

#define LOADRAW(KK, R) do {                                                   \
    const float4v z_ = float4v{0.f, 0.f, 0.f, 0.f};                           \
    _Pragma("unroll")                                                         \
    for (int rt_ = 0; rt_ < 4; ++rt_) {                                       \
        R[rt_][0] = vr[rt_] ? *(const float4v*)(ap[rt_] + (KK) * 32)     : z_;\
        R[rt_][1] = vr[rt_] ? *(const float4v*)(ap[rt_] + (KK) * 32 + 4) : z_;\
    } } while (0)

#define DOKK(KK, R) do {                                                      \
    bf16x8 a_[4], b_[4];                                                      \
    _Pragma("unroll")                                                         \
    for (int rt_ = 0; rt_ < 4; ++rt_) {                                       \
        u32x4 t_;                                                             \
        t_[0] = pk2(R[rt_][0][0], R[rt_][0][1]);                              \
        t_[1] = pk2(R[rt_][0][2], R[rt_][0][3]);                              \
        t_[2] = pk2(R[rt_][1][0], R[rt_][1][1]);                              \
        t_[3] = pk2(R[rt_][1][2], R[rt_][1][3]);                              \
        a_[rt_] = __builtin_bit_cast(bf16x8, t_);                             \
    }                                                                         \
    _Pragma("unroll")                                                         \
    for (int ct_ = 0; ct_ < 4; ++ct_)                                         \
        b_[ct_] = *(const bf16x8*)(Bs + ct_ * 8192 + (KK) * 512 + bfr);       \
    _Pragma("unroll")                                                         \
    for (int ct_ = 0; ct_ < 4; ++ct_)                                         \
        _Pragma("unroll")                                                     \
        for (int rt_ = 0; rt_ < 4; ++rt_)                                     \
            acc[rt_][ct_] = __builtin_amdgcn_mfma_f32_16x16x32_bf16(          \
                a_[rt_], b_[ct_], acc[rt_][ct_], 0, 0, 0);                    \
    } while (0)

__global__ __launch_bounds__(256, 2)
void sgl_gemm(const float* __restrict__ x,
              const unsigned short* __restrict__ wsw,
              const int* __restrict__ starts,
              const float* __restrict__ coeff,
              float* __restrict__ y)
{
    __shared__ unsigned short Bs[BS_US];   // 64 KiB

    const int tid = threadIdx.x, lane = tid & 63, wave = tid >> 6;
    const int l15 = lane & 15, l4 = lane >> 4;

    // XCD swizzle: 1080 = 8 * 135 exactly; each XCD gets 135 consecutive wk.
    const int bid = blockIdx.x;
    const int wk  = (bid & 7) * NBM_MAX + (bid >> 3);
    const int bn  = wk & 7;
    const int bmp = wk >> 3;

    // locate (group, slice) for this padded row-block
    int s[9];
#pragma unroll
    for (int i = 0; i < 9; ++i) s[i] = starts[i];
    int g = -1, lblk = 0, ab = 0;
#pragma unroll
    for (int gg = 0; gg < 8; ++gg) {
        const int c  = s[gg + 1] - s[gg];
        const int nb = (c + BROW - 1) >> 8;
        if (g < 0 && bmp < ab + nb) { g = gg; lblk = bmp - ab; }
        ab += nb;
    }
    if (g < 0) return;
    const int start = s[g];
    const int cnt   = s[g + 1] - s[g];
    const int j0    = lblk << 8;

    // A: wave streams rows [wave*64, wave*64+64); lane handles 4 rows (rt),
    // k-segment l4*8 (+kk*32), 8 fp32 = 2 float4 per (rt,kk).
    const float* ap[4];
    bool vr[4];
#pragma unroll
    for (int rt = 0; rt < 4; ++rt) {
        const int rl = wave * 64 + rt * 16 + l15;
        vr[rt] = (j0 + rl) < cnt;
        ap[rt] = x + (size_t)(start + j0 + rl) * Ud + l4 * 8;
    }
    const int bfr = l4 * 128 + l15 * 8;    // B frag us offset within (ct,kk)

    float4v e[4][2], o[4][2];
    LOADRAW(0, e);                          // overlap x latency with W-stage

    // stage W panel: 64 KiB linear, 16 x global_load_lds per thread
    const unsigned short* wB = wsw + (size_t)(g * NBN + bn) * PER_GBN_US;
#pragma unroll
    for (int i = 0; i < 16; ++i) {
        const int ous = (i * 256 + tid) * 8;
        __builtin_amdgcn_global_load_lds((gbl_uint*)(wB + ous),
                                         (lds_uint*)(Bs + ous), 16, 0, 0);
    }

    f32x4 acc[4][4];
#pragma unroll
    for (int rt = 0; rt < 4; ++rt)
#pragma unroll
        for (int ct = 0; ct < 4; ++ct)
            acc[rt][ct] = f32x4{0.f, 0.f, 0.f, 0.f};

    __syncthreads();                        // W ready (and e ready); ONLY barrier

#pragma unroll
    for (int p = 0; p < 8; ++p) {
        const int kk = p * 2;
        if (kk + 1 < KT) LOADRAW(kk + 1, o);
        DOKK(kk, e);
        if (kk + 2 < KT) LOADRAW(kk + 2, e);
        DOKK(kk + 1, o);
    }

    // epilogue: C/D col=lane&15, row=(lane>>4)*4+q; mask padded rows
    const float cf = coeff[0];
    const bool full = (j0 + BROW) <= cnt;
#pragma unroll
    for (int rt = 0; rt < 4; ++rt) {
        const int rb = wave * 64 + rt * 16 + l4 * 4;
#pragma unroll
        for (int ct = 0; ct < 4; ++ct) {
            const int col = bn * BCOL + ct * 16 + l15;
#pragma unroll
            for (int q = 0; q < 4; ++q) {
                if (full || (j0 + rb + q) < cnt)
                    y[(size_t)(start + j0 + rb + q) * Vd + col] = acc[rt][ct][q] * cf;
            }
        }
    }
}

// ---------------- safety-net fallback (ws too small; not expected) --------

__global__ __launch_bounds__(256)
void sgl_naive(const float* __restrict__ w, const float* __restrict__ x,
               const int* __restrict__ idx, const float* __restrict__ coeff,
               float* __restrict__ y)
{
    __shared__ float xs[Ud];
    const int z = blockIdx.x;
    const int g = idx[z];
    for (int u = threadIdx.x; u < Ud; u += 256) xs[u] = x[(size_t)z * Ud + u];
    __syncthreads();
    const float* Wg = w + (size_t)g * (Ud * Vd);
    const float cf = coeff[0];
    for (int v = threadIdx.x; v < Vd; v += 256) {
        float acc = 0.f;
        for (int u = 0; u < Ud; ++u) acc += xs[u] * Wg[(size_t)u * Vd + v];
        y[(size_t)z * Vd + v] = acc * cf;
    }
}

extern "C" void kernel_launch(void* const* d_in, const int* in_sizes, int n_in,
                              void* d_out, int out_size, void* d_ws, size_t ws_size,
                              hipStream_t stream) {
    const float* w     = (const float*)d_in[0];
    const float* x     = (const float*)d_in[1];
    const int*   idx   = (const int*)d_in[2];
    const float* coeff = (const float*)d_in[3];
    float* y = (float*)d_out;

    if (ws_size >= WS_NEEDED) {
        unsigned short* wsw = (unsigned short*)d_ws;
        int* starts = (int*)((char*)d_ws + (size_t)WSW_US * 2);
        hipLaunchKernelGGL(convert_w, dim3(2048), dim3(256), 0, stream,
                           w, idx, wsw, starts);
        hipLaunchKernelGGL(sgl_gemm, dim3(GRID_GEMM), dim3(256), 0, stream,
                           x, wsw, starts, coeff, y);
    } else {
        hipLaunchKernelGGL(sgl_naive, dim3(Zd), dim3(256), 0, stream,
                           w, x, idx, coeff, y);
    }
}

// Round 6
// 51.183 us; speedup vs baseline: 1.8331x; 1.8331x over previous
//
#include <hip/hip_runtime.h>
#include <stdint.h>

// Grouped linear: y[z] = coeff * x[z] @ W[idx[z]], idx sorted.
// C=8, U=V=512, Z=32768, fp32 in/out, bf16 MFMA compute.
//
// R6: single-pass x (coalesced reg-stage + cvt + ds_write), B via
// global_load_lds from pre-tiled bf16 ws, 128x128 tile BK=32, 4 waves,
// 3 blocks/CU, 2-phase dbuf with RAW s_barrier + counted vmcnt(4) so the
// A(kt+2) reg-prefetch loads stay in flight across barriers (T3/T4).

#define Cg 8
#define Ud 512
#define Vd 512
#define Zd 32768

#define BM 128
#define BN 128
#define BK 32
#define KT 16

#define TILE_US 4096             // 128*32 bf16 = 8 KiB
#define NBN 4
#define NBM_MAX 263              // sum ceil(cnt_g/128) <= 256+7
#define GRID_GEMM (NBM_MAX * NBN)

#define WSW_US (Cg * NBN * KT * TILE_US)     // 4 MiB of bf16
#define WS_NEEDED ((size_t)WSW_US * 2 + 64)

typedef __attribute__((ext_vector_type(8))) short bf16x8;
typedef __attribute__((ext_vector_type(4))) float f32x4;
typedef __attribute__((ext_vector_type(4))) unsigned short us4;
typedef __attribute__((ext_vector_type(4))) float float4v;
typedef __attribute__((ext_vector_type(4))) unsigned int u32x4;

typedef __attribute__((address_space(3))) unsigned int lds_uint;
typedef const __attribute__((address_space(1))) unsigned int gbl_uint;

__device__ __forceinline__ unsigned short f2bf(float f) {
    unsigned int u = __float_as_uint(f);
    u += 0x7fffu + ((u >> 16) & 1u);   // round-to-nearest-even
    return (unsigned short)(u >> 16);
}
__device__ __forceinline__ unsigned int pk2(float lo, float hi) {
    return (unsigned int)f2bf(lo) | ((unsigned int)f2bf(hi) << 16);
}

// Subtile layout within one [128 r][32 k] tile (ushort offset):
//   (r>>4)*512 + (k>>3)*128 + (r&15)*8 + (k&7)
// Frag read (lane l): byte = rt*1024 + l4*256 + l15*16 -> contiguous 1 KiB
// per frag across the wave: conflict-free ds_read_b128 (verified R2: 0 conf).

// ---------------- w converter (+ group starts) ----------------

__global__ __launch_bounds__(256)
void convert_w(const float* __restrict__ w, const int* __restrict__ idx,
               unsigned short* __restrict__ wsw, int* __restrict__ starts)
{
    const int t = blockIdx.x * 256 + threadIdx.x;    // 524288 tasks
    const int g   = t >> 16;
    const int rem = t & 65535;
    const int u0  = (rem >> 9) << 2;                 // 4 k-rows
    const int v   = rem & 511;
    const float* src = w + ((size_t)g << 18) + (size_t)u0 * Vd + v;
    us4 p;
    p[0] = f2bf(src[0]);
    p[1] = f2bf(src[Vd]);
    p[2] = f2bf(src[2 * Vd]);
    p[3] = f2bf(src[3 * Vd]);
    const int r = v & 127, k = u0 & 31;
    const int tile = (g * NBN + (v >> 7)) * KT + (u0 >> 5);
    const int off  = tile * TILE_US
                   + ((r >> 4) << 9) + ((k >> 3) << 7) + ((r & 15) << 3) + (k & 7);
    *(us4*)(wsw + off) = p;

    if (blockIdx.x == 0 && threadIdx.x < 9) {
        const int gq = threadIdx.x;
        int lo = 0;
        if (gq >= 8) lo = Zd;
        else {
            int hi = Zd;
            while (lo < hi) { int mid = (lo + hi) >> 1;
                              if (idx[mid] < gq) lo = mid + 1; else hi = mid; }
        }
        starts[gq] = lo;
    }
}

// ---------------- GEMM ----------------

#define LDA(KTV, A0, A1, A2, A3) do {                                         \
    const float* p_ = ax + (KTV) * BK;                                        \
    A0 = *(const float4v*)(p_);                                               \
    A1 = *(const float4v*)(p_ + 4);                                           \
    A2 = *(const float4v*)(p_ + 8);                                           \
    A3 = *(const float4v*)(p_ + 12); } while (0)

#define CVW(BUF, A0, A1, A2, A3) do {                                         \
    u32x4 w1_, w2_;                                                           \
    w1_[0] = pk2(A0[0], A0[1]); w1_[1] = pk2(A0[2], A0[3]);                   \
    w1_[2] = pk2(A1[0], A1[1]); w1_[3] = pk2(A1[2], A1[3]);                   \
    w2_[0] = pk2(A2[0], A2[1]); w2_[1] = pk2(A2[2], A2[3]);                   \
    w2_[2] = pk2(A3[0], A3[1]); w2_[3] = pk2(A3[2], A3[3]);                   \
    *(u32x4*)(&BUF[aw])       = w1_;                                          \
    *(u32x4*)(&BUF[aw + 128]) = w2_; } while (0)

#define GLB(KTV, BUF) do {                                                    \
    const unsigned short* s_ = wB + (size_t)(KTV) * TILE_US;                  \
    __builtin_amdgcn_global_load_lds((gbl_uint*)(s_ + bo),                    \
                                     (lds_uint*)(&BUF[bo]), 16, 0, 0);        \
    __builtin_amdgcn_global_load_lds((gbl_uint*)(s_ + bo + 2048),             \
                                     (lds_uint*)(&BUF[bo + 2048]), 16, 0, 0); \
  } while (0)

#define CMP(ABUF, BBUF) do {                                                  \
    bf16x8 a_[4], b_[4];                                                      \
    _Pragma("unroll")                                                         \
    for (int mi_ = 0; mi_ < 4; ++mi_)                                         \
        a_[mi_] = *(const bf16x8*)(&ABUF[((wm4 + mi_) << 9) + fr]);           \
    _Pragma("unroll")                                                         \
    for (int ni_ = 0; ni_ < 4; ++ni_)                                         \
        b_[ni_] = *(const bf16x8*)(&BBUF[((wn4 + ni_) << 9) + fr]);           \
    _Pragma("unroll")                                                         \
    for (int mi_ = 0; mi_ < 4; ++mi_)                                         \
        _Pragma("unroll")                                                     \
        for (int ni_ = 0; ni_ < 4; ++ni_)                                     \
            acc[mi_][ni_] = __builtin_amdgcn_mfma_f32_16x16x32_bf16(          \
                a_[mi_], b_[ni_], acc[mi_][ni_], 0, 0, 0);                    \
  } while (0)

#define WAITBAR(N) do {                                                       \
    asm volatile("s_waitcnt vmcnt(" #N ") lgkmcnt(0)" ::: "memory");          \
    __builtin_amdgcn_s_barrier(); } while (0)

__global__ __launch_bounds__(256, 3)
void sgl_gemm(const float* __restrict__ x,
              const unsigned short* __restrict__ wsw,
              const int* __restrict__ starts,
              const float* __restrict__ coeff,
              float* __restrict__ y)
{
    __shared__ unsigned short As[2][TILE_US];
    __shared__ unsigned short Bs[2][TILE_US];    // 32 KiB total

    const int tid = threadIdx.x, lane = tid & 63, wave = tid >> 6;
    const int l15 = lane & 15, l4 = lane >> 4;

    // bijective XCD swizzle (m204): nwg=1052, q=131, r=4; consecutive wk
    // share bmp -> the 4 bn-blocks of one x-panel land on one XCD.
    const int bid = blockIdx.x;
    const int xcd = bid & 7, io = bid >> 3;
    const int wk  = (xcd < 4) ? xcd * 132 + io : 528 + (xcd - 4) * 131 + io;
    const int bmp = wk >> 2, bn = wk & 3;

    // locate group for this padded row-block
    int s[9];
#pragma unroll
    for (int i = 0; i < 9; ++i) s[i] = starts[i];
    int g = -1, lblk = 0, ab = 0;
#pragma unroll
    for (int gg = 0; gg < 8; ++gg) {
        const int c  = s[gg + 1] - s[gg];
        const int nb = (c + BM - 1) >> 7;
        if (g < 0 && bmp < ab + nb) { g = gg; lblk = bmp - ab; }
        ab += nb;
    }
    if (g < 0) return;
    const int start = s[g];
    const int cnt   = s[g + 1] - s[g];
    const int j0    = lblk << 7;

    // A: thread t -> row t>>1 (coalesced), k-half (t&1)*16; clamp padded rows
    const int ar = tid >> 1;
    const int ak = (tid & 1) << 4;
    const int rc = (j0 + ar < cnt) ? (j0 + ar) : (cnt - 1);
    const float* ax = x + (size_t)(start + rc) * Ud + ak;
    const int aw = ((ar >> 4) << 9) + ((ak >> 3) << 7) + ((ar & 15) << 3);

    // B: linear gload_lds from pre-tiled ws
    const unsigned short* wB = wsw + (size_t)((g * NBN + bn) * KT) * TILE_US;
    const int bo = tid * 8;

    const int wm4 = (wave >> 1) << 2;
    const int wn4 = (wave & 1) << 2;
    const int fr  = (l4 << 7) + (l15 << 3);

    f32x4 acc[4][4];
#pragma unroll
    for (int mi = 0; mi < 4; ++mi)
#pragma unroll
        for (int ni = 0; ni < 4; ++ni)
            acc[mi][ni] = f32x4{0.f, 0.f, 0.f, 0.f};

    float4v e0, e1, e2, e3, o0, o1, o2, o3;

    // prologue: A(0)->e, B(0), A(1)->o ; cvt A(0); barrier leaves A(1) flying
    LDA(0, e0, e1, e2, e3);
    __builtin_amdgcn_sched_barrier(0);
    GLB(0, Bs[0]);
    __builtin_amdgcn_sched_barrier(0);
    LDA(1, o0, o1, o2, o3);
    __builtin_amdgcn_sched_barrier(0);
    CVW(As[0], e0, e1, e2, e3);
    WAITBAR(4);

    // steady state: iter kt stages B(kt+1)+A(kt+2), cvts A(kt+1), computes kt.
    // Barrier waits vmcnt(4): B(kt+1) done, A(kt+2) reg-loads stay in flight.
#pragma unroll
    for (int kt = 0; kt < 14; ++kt) {
        if ((kt & 1) == 0) {
            GLB(kt + 1, Bs[1]);
            __builtin_amdgcn_sched_barrier(0);
            LDA(kt + 2, e0, e1, e2, e3);
            __builtin_amdgcn_sched_barrier(0);
            CVW(As[1], o0, o1, o2, o3);
            CMP(As[0], Bs[0]);
        } else {
            GLB(kt + 1, Bs[0]);
            __builtin_amdgcn_sched_barrier(0);
            LDA(kt + 2, o0, o1, o2, o3);
            __builtin_amdgcn_sched_barrier(0);
            CVW(As[0], e0, e1, e2, e3);
            CMP(As[1], Bs[1]);
        }
        WAITBAR(4);
    }
    // kt = 14 (A(15) is in o; no more prefetch)
    GLB(15, Bs[1]);
    __builtin_amdgcn_sched_barrier(0);
    CVW(As[1], o0, o1, o2, o3);
    CMP(As[0], Bs[0]);
    WAITBAR(0);
    // kt = 15
    CMP(As[1], Bs[1]);

    // epilogue: C/D col=lane&15, row=(lane>>4)*4+q; mask padded rows
    const float cf = coeff[0];
    const bool full = (j0 + BM) <= cnt;
#pragma unroll
    for (int mi = 0; mi < 4; ++mi) {
        const int rb = ((wave >> 1) << 6) + mi * 16 + l4 * 4;
#pragma unroll
        for (int ni = 0; ni < 4; ++ni) {
            const int c = bn * BN + ((wave & 1) << 6) + ni * 16 + l15;
#pragma unroll
            for (int q = 0; q < 4; ++q) {
                if (full || (j0 + rb + q) < cnt)
                    y[(size_t)(start + j0 + rb + q) * Vd + c] = acc[mi][ni][q] * cf;
            }
        }
    }
}

// ---------------- safety-net fallback (ws too small; not expected) --------

__global__ __launch_bounds__(256)
void sgl_naive(const float* __restrict__ w, const float* __restrict__ x,
               const int* __restrict__ idx, const float* __restrict__ coeff,
               float* __restrict__ y)
{
    __shared__ float xs[Ud];
    const int z = blockIdx.x;
    const int g = idx[z];
    for (int u = threadIdx.x; u < Ud; u += 256) xs[u] = x[(size_t)z * Ud + u];
    __syncthreads();
    const float* Wg = w + (size_t)g * (Ud * Vd);
    const float cf = coeff[0];
    for (int v = threadIdx.x; v < Vd; v += 256) {
        float acc = 0.f;
        for (int u = 0; u < Ud; ++u) acc += xs[u] * Wg[(size_t)u * Vd + v];
        y[(size_t)z * Vd + v] = acc * cf;
    }
}

extern "C" void kernel_launch(void* const* d_in, const int* in_sizes, int n_in,
                              void* d_out, int out_size, void* d_ws, size_t ws_size,
                              hipStream_t stream) {
    const float* w     = (const float*)d_in[0];
    const float* x     = (const float*)d_in[1];
    const int*   idx   = (const int*)d_in[2];
    const float* coeff = (const float*)d_in[3];
    float* y = (float*)d_out;

    if (ws_size >= WS_NEEDED) {
        unsigned short* wsw = (unsigned short*)d_ws;
        int* starts = (int*)((char*)d_ws + (size_t)WSW_US * 2);
        hipLaunchKernelGGL(convert_w, dim3(2048), dim3(256), 0, stream,
                           w, idx, wsw, starts);
        hipLaunchKernelGGL(sgl_gemm, dim3(GRID_GEMM), dim3(256), 0, stream,
                           x, wsw, starts, coeff, y);
    } else {
        hipLaunchKernelGGL(sgl_naive, dim3(Zd), dim3(256), 0, stream,
                           w, x, idx, coeff, y);
    }
}